// Round 10
// baseline (5060.060 us; speedup 1.0000x reference)
//
#include <hip/hip_runtime.h>
#include <hip/hip_bf16.h>

typedef __bf16 bf16x8 __attribute__((ext_vector_type(8)));
typedef float f32x4 __attribute__((ext_vector_type(4)));

#define HSZ (1024*512)      // h/c slot elems
#define WSZ (2048*512)      // weight matrix elems

__device__ __forceinline__ float fsig(float x){ return 1.0f/(1.0f+__expf(-x)); }
__device__ __forceinline__ float ftanh(float x){ return 1.0f - 2.0f/(__expf(2.0f*x)+1.0f); }
__device__ __forceinline__ float bf2f(ushort u){ return __uint_as_float(((unsigned)u) << 16); }
__device__ __forceinline__ ushort f2bf(float f){
  __hip_bfloat16 b = __float2bfloat16(f);
  return *reinterpret_cast<const ushort*>(&b);
}

// weights: normal caching -> L2-resident across the whole persistent run
__device__ __forceinline__ void gload16w(const void* g, void* l){
  __builtin_amdgcn_global_load_lds((const __attribute__((address_space(1))) void*)g,
                                   (__attribute__((address_space(3))) void*)l, 16, 0, 0);
}
// activations: sc1 (agent scope, aux bit4) -> bypass L1/L2, coherent read from L3
__device__ __forceinline__ void gload16a(const void* g, void* l){
  __builtin_amdgcn_global_load_lds((const __attribute__((address_space(1))) void*)g,
                                   (__attribute__((address_space(3))) void*)l, 16, 0, 16);
}
// h store: agent-scope write-through; visible to other XCDs once vmcnt==0
__device__ __forceinline__ void store_h_sc1(ushort* p, ushort v){
  asm volatile("global_store_short %0, %1, off sc1" :: "v"(p), "v"((uint)v) : "memory");
}

struct CP {
  const ushort* A0; const ushort* W0;
  const ushort* A1; const ushort* W1;
  const float*  xs; const float* Ws; int ks;
  const float*  bias;
  ushort* c; ushort* h;
};

// ---- 64x128 cell (R4-proven geometry): 4 waves, dbuf 2x24KB, vmcnt(6) ----
__device__ __forceinline__ void run_cell64(const CP P, char* ldsb, int m0, int h0q)
{
  const int tid = threadIdx.x;
  const int w = tid >> 6, lane = tid & 63;
  const int wm = w >> 1, wn = w & 1;
  const int colL = lane & 15, kgrp = lane >> 4;
  const int srow = lane >> 3, scch = lane & 7;

  const ushort* Aseg[2] = { P.A0, P.A1 };
  const ushort* Wseg[2] = { P.W0, P.W1 };
  const int nt = (P.A1 != nullptr) ? 16 : 8;

  auto stage = [&](int buf, int it){
    const int seg = it >> 3, k0 = (it & 7) << 6;
    const ushort* A  = Aseg[seg];
    const ushort* Wt = Wseg[seg];
    ushort* Als = (ushort*)(ldsb + buf*24576);
    ushort* Bls = Als + 4096;
    #pragma unroll
    for (int q = 0; q < 2; ++q){
      const int base = (w<<4) + (q<<3);
      const int r  = base + srow;
      const int sw = (scch ^ (r & 7)) << 3;
      gload16a(A + (size_t)(m0 + r)*512 + k0 + sw, Als + (base<<6));
    }
    #pragma unroll
    for (int q = 0; q < 4; ++q){
      const int base = (w<<5) + (q<<3);
      const int r  = base + srow;
      const int g = (r >> 4) & 3, hp = r >> 6, hh = r & 15;
      const int sw = (scch ^ (r & 7)) << 3;
      gload16w(Wt + ((size_t)(g<<9) + h0q + (hp<<4) + hh)*512 + k0 + sw, Bls + (base<<6));
    }
  };

  f32x4 acc[2][4] = {};
  stage(0, 0);
  for (int it = 0; it < nt; ++it){
    const int cur = it & 1;
    if (it + 1 < nt) stage(cur ^ 1, it + 1);
    __builtin_amdgcn_sched_barrier(0);
    if (it + 1 < nt) asm volatile("s_waitcnt vmcnt(6)" ::: "memory");
    else             asm volatile("s_waitcnt vmcnt(0)" ::: "memory");
    __builtin_amdgcn_s_barrier();
    __builtin_amdgcn_sched_barrier(0);
    const ushort* Als = (const ushort*)(ldsb + cur*24576);
    const ushort* Bls = Als + 4096;
    const int ar0 = (wm<<5) + colL;
    const int ar1 = ar0 + 16;
    __builtin_amdgcn_s_setprio(1);
    #pragma unroll
    for (int kh = 0; kh < 2; ++kh){
      const int cb = (kh<<2) + kgrp;
      bf16x8 av0 = *(const bf16x8*)(Als + ar0*64 + ((cb ^ (ar0 & 7)) << 3));
      bf16x8 av1 = *(const bf16x8*)(Als + ar1*64 + ((cb ^ (ar1 & 7)) << 3));
      #pragma unroll
      for (int nf = 0; nf < 4; ++nf){
        const int br = (wn<<6) + (nf<<4) + colL;
        bf16x8 bv = *(const bf16x8*)(Bls + br*64 + ((cb ^ (br & 7)) << 3));
        acc[0][nf] = __builtin_amdgcn_mfma_f32_16x16x32_bf16(av0, bv, acc[0][nf], 0, 0, 0);
        acc[1][nf] = __builtin_amdgcn_mfma_f32_16x16x32_bf16(av1, bv, acc[1][nf], 0, 0, 0);
      }
    }
    __builtin_amdgcn_s_setprio(0);
    __builtin_amdgcn_sched_barrier(0);
    __builtin_amdgcn_s_barrier();
  }

  const int h = h0q + (wn << 4) + colL;
  float bia[4], wsv[4][4];
  #pragma unroll
  for (int g = 0; g < 4; ++g) bia[g] = P.bias[(g << 9) + h];
  if (P.ks > 0){
    #pragma unroll
    for (int g = 0; g < 4; ++g)
      #pragma unroll
      for (int k = 0; k < 4; ++k)
        wsv[g][k] = (k < P.ks) ? P.Ws[(size_t)((g << 9) + h)*P.ks + k] : 0.f;
  }
  #pragma unroll
  for (int mf = 0; mf < 2; ++mf){
    const int mB = m0 + (wm << 5) + (mf << 4) + (kgrp << 2);
    float xv[4][4];
    if (P.ks > 0){
      #pragma unroll
      for (int r = 0; r < 4; ++r)
        #pragma unroll
        for (int k = 0; k < 4; ++k)
          xv[r][k] = (k < P.ks) ? P.xs[(size_t)(mB + r)*P.ks + k] : 0.f;
    }
    #pragma unroll
    for (int r = 0; r < 4; ++r){
      const int m = mB + r;
      float gv[4];
      #pragma unroll
      for (int g = 0; g < 4; ++g){
        float t_ = acc[mf][g][r] + bia[g];
        if (P.ks > 0){
          #pragma unroll
          for (int k = 0; k < 4; ++k) t_ += xv[r][k]*wsv[g][k];
        }
        gv[g] = t_;
      }
      const float iG = fsig(gv[0]);
      const float fG = fsig(gv[1]);
      const float gG = ftanh(gv[2]);
      const float oG = fsig(gv[3]);
      const size_t off = (size_t)m*512 + h;
      const float cn = fG*bf2f(P.c[off]) + iG*gG;
      P.c[off] = f2bf(cn);
      store_h_sc1(&P.h[off], f2bf(oG*ftanh(cn)));
    }
  }
}

// ---- 32x128 cell (R9-proven): 4 waves, dbuf 2x20KB, vmcnt(5) ----
__device__ __forceinline__ void run_cell32(const CP P, char* ldsb, int m0, int h0q)
{
  const int tid = threadIdx.x;
  const int w = tid >> 6, lane = tid & 63;
  const int wm = w >> 1, wn = w & 1;
  const int colL = lane & 15, kgrp = lane >> 4;

  const ushort* Aseg[2] = { P.A0, P.A1 };
  const ushort* Wseg[2] = { P.W0, P.W1 };
  const int nt = (P.A1 != nullptr) ? 16 : 8;

  auto stage = [&](int buf, int it){
    const int seg = it >> 3, k0 = (it & 7) << 6;
    const ushort* A  = Aseg[seg];
    const ushort* Wt = Wseg[seg];
    ushort* Als = (ushort*)(ldsb + buf*20480);
    ushort* Bls = Als + 2048;
    {
      const int r = tid >> 3, cc = tid & 7;
      const int sw = (cc ^ (r & 7)) << 3;
      gload16a(A + (size_t)(m0 + r)*512 + k0 + sw, Als + ((w << 3) << 6));
    }
    #pragma unroll
    for (int q = 0; q < 4; ++q){
      const int base = (q << 5) + (w << 3);
      const int r = base + (lane >> 3), cc = lane & 7;
      const int g = (r >> 4) & 3, hp = r >> 6, hh = r & 15;
      const int sw = (cc ^ (r & 7)) << 3;
      gload16w(Wt + ((size_t)(g << 9) + h0q + (hp << 4) + hh)*512 + k0 + sw,
               Bls + (base << 6));
    }
  };

  f32x4 acc[4] = {};
  stage(0, 0);
  for (int it = 0; it < nt; ++it){
    const int cur = it & 1;
    if (it + 1 < nt) stage(cur ^ 1, it + 1);
    __builtin_amdgcn_sched_barrier(0);
    if (it + 1 < nt) asm volatile("s_waitcnt vmcnt(5)" ::: "memory");
    else             asm volatile("s_waitcnt vmcnt(0)" ::: "memory");
    __builtin_amdgcn_s_barrier();
    __builtin_amdgcn_sched_barrier(0);
    const ushort* Als = (const ushort*)(ldsb + cur*20480);
    const ushort* Bls = Als + 2048;
    const int ar = (wm << 4) + colL;
    __builtin_amdgcn_s_setprio(1);
    #pragma unroll
    for (int kh = 0; kh < 2; ++kh){
      const int cb = (kh << 2) + kgrp;
      bf16x8 av = *(const bf16x8*)(Als + ar*64 + ((cb ^ (ar & 7)) << 3));
      #pragma unroll
      for (int nf = 0; nf < 4; ++nf){
        const int br = (wn << 6) + (nf << 4) + colL;
        bf16x8 bv = *(const bf16x8*)(Bls + br*64 + ((cb ^ (br & 7)) << 3));
        acc[nf] = __builtin_amdgcn_mfma_f32_16x16x32_bf16(av, bv, acc[nf], 0, 0, 0);
      }
    }
    __builtin_amdgcn_s_setprio(0);
    __builtin_amdgcn_sched_barrier(0);
    __builtin_amdgcn_s_barrier();
  }

  const int h  = h0q + (wn << 4) + colL;
  const int mB = m0 + (wm << 4) + (kgrp << 2);
  float bia[4], wsv[4][4], xv[4][4];
  #pragma unroll
  for (int g = 0; g < 4; ++g) bia[g] = P.bias[(g << 9) + h];
  if (P.ks > 0){
    #pragma unroll
    for (int g = 0; g < 4; ++g)
      #pragma unroll
      for (int k = 0; k < 4; ++k)
        wsv[g][k] = (k < P.ks) ? P.Ws[(size_t)((g << 9) + h)*P.ks + k] : 0.f;
    #pragma unroll
    for (int r = 0; r < 4; ++r)
      #pragma unroll
      for (int k = 0; k < 4; ++k)
        xv[r][k] = (k < P.ks) ? P.xs[(size_t)(mB + r)*P.ks + k] : 0.f;
  }
  #pragma unroll
  for (int r = 0; r < 4; ++r){
    const int m = mB + r;
    float gv[4];
    #pragma unroll
    for (int g = 0; g < 4; ++g){
      float t_ = acc[g][r] + bia[g];
      if (P.ks > 0){
        #pragma unroll
        for (int k = 0; k < 4; ++k) t_ += xv[r][k]*wsv[g][k];
      }
      gv[g] = t_;
    }
    const float iG = fsig(gv[0]);
    const float fG = fsig(gv[1]);
    const float gG = ftanh(gv[2]);
    const float oG = fsig(gv[3]);
    const size_t off = (size_t)m*512 + h;
    const float cn = fG*bf2f(P.c[off]) + iG*gG;
    P.c[off] = f2bf(cn);
    store_h_sc1(&P.h[off], f2bf(oG*ftanh(cn)));
  }
}

struct PersistP {
  const float* x; const float* Wih0f;
  const ushort *eWhh0, *eWih1, *eWhh1, *eWih2, *eWhh2;
  const float* dec_in; const float* dWih0f;
  const ushort *wcomb, *dWhh0, *dWih1, *dWhh1, *dWih2, *dWhh2;
  const float* biases;
  ushort *h0, *h1, *h2, *h2hist;
  ushort *c0, *c1, *c2;
  const float *linW, *linb; float* outp;
  uint* flags;   // [0]=census; [32+x*32]=cnt; [288+x*32]=arrive; [520]=global epoch
};

// global 2-level barrier: per-XCD arrive (parallel lines) -> one add to global epoch.
// relaxed atomics only; NO cache flush/invalidate (weights stay L2-resident).
__device__ __forceinline__ void gbar(uint* F, int xcc, int n, int nact, int epoch){
  __syncthreads();
  if (threadIdx.x == 0){
    asm volatile("s_waitcnt vmcnt(0) lgkmcnt(0)" ::: "memory");
    uint a = __hip_atomic_fetch_add(&F[288 + xcc*32], 1u, __ATOMIC_RELAXED, __HIP_MEMORY_SCOPE_AGENT);
    if (a == (uint)(n*epoch) - 1u)
      __hip_atomic_fetch_add(&F[520], 1u, __ATOMIC_RELAXED, __HIP_MEMORY_SCOPE_AGENT);
    while (__hip_atomic_load(&F[520], __ATOMIC_RELAXED, __HIP_MEMORY_SCOPE_AGENT) < (uint)(nact*epoch))
      __builtin_amdgcn_s_sleep(2);
  }
  __syncthreads();
}

__global__ __launch_bounds__(256, 3) void lstm_persist(PersistP P){
  __shared__ char lds[49152];
  __shared__ int sh_widx, sh_n, sh_np, sh_nact, sh_rank, sh_pair[8];
  uint xcc;
  asm volatile("s_getreg_b32 %0, hwreg(HW_REG_XCC_ID)" : "=s"(xcc));
  xcc &= 7;
  if (threadIdx.x == 0){
    uint* F = P.flags;
    int widx = (int)__hip_atomic_fetch_add(&F[32 + xcc*32], 1u, __ATOMIC_RELAXED, __HIP_MEMORY_SCOPE_AGENT);
    __hip_atomic_fetch_add(&F[0], 1u, __ATOMIC_RELAXED, __HIP_MEMORY_SCOPE_AGENT);
    while (__hip_atomic_load(&F[0], __ATOMIC_RELAXED, __HIP_MEMORY_SCOPE_AGENT) < gridDim.x)
      __builtin_amdgcn_s_sleep(2);
    int cnt[8]; int nact = 0, rank = 0;
    for (int i = 0; i < 8; ++i){
      cnt[i] = (int)__hip_atomic_load(&F[32 + i*32], __ATOMIC_RELAXED, __HIP_MEMORY_SCOPE_AGENT);
      if (cnt[i] > 0) ++nact;
      if (i < (int)xcc) rank += cnt[i];
    }
    int first = 0; while (first < 8 && cnt[first] == 0) ++first;
    int np = 0;
    for (int pr = 0; pr < 8; ++pr){
      int owner = cnt[pr] ? pr : first;
      if (owner == (int)xcc) sh_pair[np++] = pr;
    }
    sh_np = np; sh_widx = widx; sh_n = cnt[xcc]; sh_nact = nact; sh_rank = rank + widx;
  }
  __syncthreads();
  const int n = sh_n, widx = sh_widx, np = sh_np, nact = sh_nact;
  uint* F = P.flags;
  int epoch = 0;

  // ---- encoder: 66 wavefront steps; tiles = pair x {ht,ht+8} x 3 layers x 16 batch-tiles ----
  for (int s = 0; s < 66; ++s){
    const int ntile = np * 96;
    for (int tau = widx; tau < ntile; tau += n){
      const int pi  = tau / 96, rem = tau % 96;
      const int sub = rem / 48, rem2 = rem % 48;
      const int l = rem2 >> 4, bt = rem2 & 15;
      const int ht = sh_pair[pi] + (sub << 3);
      const int t = s - l;
      if (t < 0 || t > 63) continue;
      const int p = t & 1;
      const int m0 = bt << 6, h0q = ht << 5;
      CP c;
      if (l == 0){
        c = { P.h0 + (size_t)(p^1)*HSZ, P.eWhh0, nullptr, nullptr,
              P.x + (size_t)t*4096, P.Wih0f, 4, P.biases, P.c0, P.h0 + (size_t)p*HSZ };
      } else if (l == 1){
        c = { P.h0 + (size_t)p*HSZ, P.eWih1, P.h1 + (size_t)(p^1)*HSZ, P.eWhh1,
              nullptr, nullptr, 0, P.biases + 2048, P.c1, P.h1 + (size_t)p*HSZ };
      } else {
        c = { P.h1 + (size_t)p*HSZ, P.eWih2, P.h2 + (size_t)(p^1)*HSZ, P.eWhh2,
              nullptr, nullptr, 0, P.biases + 4096, P.c2, P.h2 + (size_t)p*HSZ };
      }
      run_cell64(c, lds, m0, h0q);
    }
    ++epoch;
    gbar(F, (int)xcc, n, nact, epoch);
  }

  // ---- decoder: 32 t x 3 phases; tiles = pair x {ht,ht+8} x 32 batch-tiles (32-wide) ----
  for (int t = 0; t < 32; ++t){
    const int p = t & 1;
    for (int ph = 0; ph < 3; ++ph){
      const int ntile = np * 64;
      for (int tau = widx; tau < ntile; tau += n){
        const int pi = tau >> 6, rem = tau & 63;
        const int sub = rem >> 5, bt = rem & 31;
        const int ht = sh_pair[pi] + (sub << 3);
        const int m0 = bt << 5, h0q = ht << 5;
        CP c;
        if (ph == 0){
          if (t == 0)
            c = { P.h0 + (size_t)HSZ, P.dWhh0, nullptr, nullptr,
                  P.dec_in, P.dWih0f, 2, P.biases + 3*2048, P.c0, P.h0 };
          else
            c = { P.h2hist + (size_t)(t-1)*HSZ, P.wcomb, P.h0 + (size_t)(p^1)*HSZ, P.dWhh0,
                  nullptr, nullptr, 0, P.biases + 4*2048, P.c0, P.h0 + (size_t)p*HSZ };
        } else if (ph == 1){
          c = { P.h0 + (size_t)p*HSZ, P.dWih1, P.h1 + (size_t)(p^1)*HSZ, P.dWhh1,
                nullptr, nullptr, 0, P.biases + 5*2048, P.c1, P.h1 + (size_t)p*HSZ };
        } else {
          const ushort* a1 = (t == 0) ? (P.h2 + (size_t)HSZ) : (P.h2hist + (size_t)(t-1)*HSZ);
          c = { P.h1 + (size_t)p*HSZ, P.dWih2, a1, P.dWhh2,
                nullptr, nullptr, 0, P.biases + 6*2048, P.c2, P.h2hist + (size_t)t*HSZ };
        }
        run_cell32(c, lds, m0, h0q);
      }
      ++epoch;
      gbar(F, (int)xcc, n, nact, epoch);
    }
  }

  // ---- final linear over h2hist (normal loads; L3 is authoritative) ----
  {
    const int w = threadIdx.x >> 6, lane = threadIdx.x & 63;
    const int grank = sh_rank;
    const int stride = (int)gridDim.x * 4;
    for (int rr = grank*4 + w; rr < 32*1024; rr += stride){
      const int t = rr >> 10, m = rr & 1023;
      const ushort* hrow = P.h2hist + (size_t)t*HSZ + (size_t)m*512;
      float p0 = 0.f, p1 = 0.f;
      #pragma unroll
      for (int kk = 0; kk < 8; ++kk){
        const int k = lane + kk*64;
        const float hv = bf2f(hrow[k]);
        p0 += hv * P.linW[k];
        p1 += hv * P.linW[512 + k];
      }
      #pragma unroll
      for (int off = 32; off > 0; off >>= 1){
        p0 += __shfl_down(p0, off);
        p1 += __shfl_down(p1, off);
      }
      if (lane == 0){
        float* o = P.outp + ((size_t)t*1024 + m)*2;
        o[0] = p0 + P.linb[0];
        o[1] = p1 + P.linb[1];
      }
    }
  }
}

// ---------------- fallback per-launch kernels (small-ws path) ----------------
__global__ __launch_bounds__(256) void cell32_k(CP c){
  __shared__ char lds[49152];
  const int bx = blockIdx.x & 31, ht = blockIdx.x >> 5;
  run_cell32(c, lds, bx*32, ht*32);
}

__global__ __launch_bounds__(256) void dec_linear(const ushort* __restrict__ h2,
    const float* __restrict__ linW, const float* __restrict__ linb,
    float* __restrict__ outp, float* __restrict__ di){
  int tid = threadIdx.x, w = tid >> 6, lane = tid & 63;
  int mbase = blockIdx.x*32 + w*8;
  for (int r = 0; r < 8; ++r){
    int m = mbase + r;
    float p0 = 0.f, p1 = 0.f;
    #pragma unroll
    for (int kk = 0; kk < 8; ++kk){
      int k = lane + kk*64;
      float hv = bf2f(h2[(size_t)m*512 + k]);
      p0 += hv * linW[k];
      p1 += hv * linW[512 + k];
    }
    #pragma unroll
    for (int off = 32; off > 0; off >>= 1){
      p0 += __shfl_down(p0, off);
      p1 += __shfl_down(p1, off);
    }
    if (lane == 0){
      float o0 = p0 + linb[0], o1 = p1 + linb[1];
      outp[m*2]   = o0; outp[m*2+1] = o1;
      di[m*2]     = o0; di[m*2+1]   = o1;
    }
  }
}

// ---------------- small utility kernels ----------------
__global__ void f2b4(const float4* __restrict__ src, ushort4* __restrict__ dst, int n4){
  int i = blockIdx.x*blockDim.x + threadIdx.x;
  if (i < n4){
    float4 v = src[i];
    ushort4 r;
    r.x = f2bf(v.x); r.y = f2bf(v.y); r.z = f2bf(v.z); r.w = f2bf(v.w);
    dst[i] = r;
  }
}

__global__ void init_decin(const float* __restrict__ x, float* __restrict__ di){
  int i = blockIdx.x*blockDim.x + threadIdx.x;
  if (i < 2048){ int m = i >> 1, j = i & 1; di[i] = x[(size_t)63*4096 + m*4 + j]; }
}

__global__ void make_wcomb(const float* __restrict__ dWih0, const float* __restrict__ linW,
                           ushort* __restrict__ wc){
  int i = blockIdx.x*blockDim.x + threadIdx.x;
  if (i < 2048*512){
    int n = i >> 9, k = i & 511;
    wc[i] = f2bf(dWih0[n*2]*linW[k] + dWih0[n*2+1]*linW[512+k]);
  }
}

__global__ void prep_bias(const float* ebih0, const float* ebhh0,
                          const float* ebih, const float* ebhh,
                          const float* dbih0, const float* dbhh0,
                          const float* dbih, const float* dbhh,
                          const float* dWih0, const float* linb, float* bout){
  int n = blockIdx.x*blockDim.x + threadIdx.x;
  if (n >= 2048) return;
  bout[n]        = ebih0[n] + ebhh0[n];
  bout[2048+n]   = ebih[n] + ebhh[n];
  bout[2*2048+n] = ebih[2048+n] + ebhh[2048+n];
  float d0 = dbih0[n] + dbhh0[n];
  bout[3*2048+n] = d0;
  bout[4*2048+n] = d0 + dWih0[n*2]*linb[0] + dWih0[n*2+1]*linb[1];
  bout[5*2048+n] = dbih[n] + dbhh[n];
  bout[6*2048+n] = dbih[2048+n] + dbhh[2048+n];
}

extern "C" void kernel_launch(void* const* d_in, const int* in_sizes, int n_in,
                              void* d_out, int out_size, void* d_ws, size_t ws_size,
                              hipStream_t stream)
{
  const float* x        = (const float*)d_in[0];
  const float* enc_Wih0 = (const float*)d_in[1];
  const float* enc_Whh0 = (const float*)d_in[2];
  const float* enc_bih0 = (const float*)d_in[3];
  const float* enc_bhh0 = (const float*)d_in[4];
  const float* enc_Wih  = (const float*)d_in[5];
  const float* enc_Whh  = (const float*)d_in[6];
  const float* enc_bih  = (const float*)d_in[7];
  const float* enc_bhh  = (const float*)d_in[8];
  const float* dec_Wih0 = (const float*)d_in[9];
  const float* dec_Whh0 = (const float*)d_in[10];
  const float* dec_bih0 = (const float*)d_in[11];
  const float* dec_bhh0 = (const float*)d_in[12];
  const float* dec_Wih  = (const float*)d_in[13];
  const float* dec_Whh  = (const float*)d_in[14];
  const float* dec_bih  = (const float*)d_in[15];
  const float* dec_bhh  = (const float*)d_in[16];
  const float* lin_W    = (const float*)d_in[17];
  const float* lin_b    = (const float*)d_in[18];

  const bool big = ws_size >= 69271552ull;

  ushort* wb     = (ushort*)d_ws;
  ushort* eWhh0b = wb;
  ushort* eWihb  = wb + (size_t)WSZ;
  ushort* eWhhb  = wb + 3*(size_t)WSZ;
  ushort* dWhh0b = wb + 5*(size_t)WSZ;
  ushort* dWihb  = wb + 6*(size_t)WSZ;
  ushort* dWhhb  = wb + 8*(size_t)WSZ;
  ushort* wcombb = wb + 10*(size_t)WSZ;
  ushort* hbuf   = wb + (big ? 11 : 10)*(size_t)WSZ;
  ushort* h2hist = hbuf + 6*(size_t)HSZ;
  ushort* cbuf   = h2hist + (big ? 32*(size_t)HSZ : 0);
  float*  dec_in = (float*)(cbuf + 3*(size_t)HSZ);
  float*  biases = dec_in + 2048;
  uint*   flags  = (uint*)(biases + 7*2048);

  ushort* h0 = hbuf;
  ushort* h1 = hbuf + 2*(size_t)HSZ;
  ushort* h2 = hbuf + 4*(size_t)HSZ;
  ushort *c0 = cbuf, *c1 = cbuf + (size_t)HSZ, *c2 = cbuf + 2*(size_t)HSZ;

  hipMemsetAsync(hbuf, 0, 6*(size_t)HSZ*2, stream);
  hipMemsetAsync(cbuf, 0, 3*(size_t)HSZ*2, stream);
  hipMemsetAsync(flags, 0, 4096, stream);

  const int thr = 256;
  {
    struct { const float* s; ushort* d; size_t n; } cv[6] = {
      {enc_Whh0, eWhh0b, WSZ}, {enc_Wih, eWihb, 2*(size_t)WSZ}, {enc_Whh, eWhhb, 2*(size_t)WSZ},
      {dec_Whh0, dWhh0b, WSZ}, {dec_Wih, dWihb, 2*(size_t)WSZ}, {dec_Whh, dWhhb, 2*(size_t)WSZ},
    };
    for (int i = 0; i < 6; ++i){
      int n4 = (int)(cv[i].n/4);
      f2b4<<<(n4+thr-1)/thr, thr, 0, stream>>>((const float4*)cv[i].s, (ushort4*)cv[i].d, n4);
    }
  }
  if (big) make_wcomb<<<4096, thr, 0, stream>>>(dec_Wih0, lin_W, wcombb);
  prep_bias<<<8, thr, 0, stream>>>(enc_bih0, enc_bhh0, enc_bih, enc_bhh,
                                   dec_bih0, dec_bhh0, dec_bih, dec_bhh,
                                   dec_Wih0, lin_b, biases);
  init_decin<<<8, thr, 0, stream>>>(x, dec_in);

  if (big){
    PersistP PP = {
      x, enc_Wih0,
      eWhh0b, eWihb, eWhhb, eWihb + (size_t)WSZ, eWhhb + (size_t)WSZ,
      dec_in, dec_Wih0,
      wcombb, dWhh0b, dWihb, dWhhb, dWihb + (size_t)WSZ, dWhhb + (size_t)WSZ,
      biases,
      h0, h1, h2, h2hist,
      c0, c1, c2,
      lin_W, lin_b, (float*)d_out,
      flags
    };
    lstm_persist<<<768, thr, 0, stream>>>(PP);
  } else {
    for (int s = 0; s < 66; ++s){
      for (int l = 0; l < 3; ++l){
        const int t = s - l;
        if (t < 0 || t > 63) continue;
        const int p = t & 1;
        CP c;
        if (l == 0)
          c = { h0 + (size_t)(p^1)*HSZ, eWhh0b, nullptr, nullptr,
                x + (size_t)t*4096, enc_Wih0, 4, biases, c0, h0 + (size_t)p*HSZ };
        else if (l == 1)
          c = { h0 + (size_t)p*HSZ, eWihb, h1 + (size_t)(p^1)*HSZ, eWhhb,
                nullptr, nullptr, 0, biases + 2048, c1, h1 + (size_t)p*HSZ };
        else
          c = { h1 + (size_t)p*HSZ, eWihb + (size_t)WSZ, h2 + (size_t)(p^1)*HSZ, eWhhb + (size_t)WSZ,
                nullptr, nullptr, 0, biases + 4096, c2, h2 + (size_t)p*HSZ };
        cell32_k<<<512, thr, 0, stream>>>(c);
      }
    }
    int cur0 = 1, cur1 = 1, cur2 = 1;
    for (int t = 0; t < 32; ++t){
      CP P0 = { h0 + (size_t)cur0*HSZ, dWhh0b, nullptr, nullptr,
                dec_in, dec_Wih0, 2, biases + 3*2048, c0, h0 + (size_t)(cur0^1)*HSZ };
      cell32_k<<<512, thr, 0, stream>>>(P0); cur0 ^= 1;
      CP P1 = { h0 + (size_t)cur0*HSZ, dWihb, h1 + (size_t)cur1*HSZ, dWhhb,
                nullptr, nullptr, 0, biases + 5*2048, c1, h1 + (size_t)(cur1^1)*HSZ };
      cell32_k<<<512, thr, 0, stream>>>(P1); cur1 ^= 1;
      CP P2 = { h1 + (size_t)cur1*HSZ, dWihb + (size_t)WSZ,
                h2 + (size_t)cur2*HSZ, dWhhb + (size_t)WSZ,
                nullptr, nullptr, 0, biases + 6*2048, c2, h2 + (size_t)(cur2^1)*HSZ };
      cell32_k<<<512, thr, 0, stream>>>(P2); cur2 ^= 1;
      dec_linear<<<32, thr, 0, stream>>>(h2 + (size_t)cur2*HSZ, lin_W, lin_b,
                                         (float*)d_out + (size_t)t*2048, dec_in);
    }
  }
}

// Round 11
// 3084.942 us; speedup vs baseline: 1.6402x; 1.6402x over previous
//
#include <hip/hip_runtime.h>
#include <hip/hip_bf16.h>

typedef __bf16 bf16x8 __attribute__((ext_vector_type(8)));
typedef float f32x4 __attribute__((ext_vector_type(4)));

#define HSZ (1024*512)      // h/c slot elems
#define WSZ (2048*512)      // weight matrix elems

__device__ __forceinline__ float fsig(float x){ return 1.0f/(1.0f+__expf(-x)); }
__device__ __forceinline__ float ftanh(float x){ return 1.0f - 2.0f/(__expf(2.0f*x)+1.0f); }
__device__ __forceinline__ float bf2f(ushort u){ return __uint_as_float(((unsigned)u) << 16); }
__device__ __forceinline__ ushort f2bf(float f){
  __hip_bfloat16 b = __float2bfloat16(f);
  return *reinterpret_cast<const ushort*>(&b);
}

__device__ __forceinline__ void gload16(const void* g, void* l){
  __builtin_amdgcn_global_load_lds((const __attribute__((address_space(1))) void*)g,
                                   (__attribute__((address_space(3))) void*)l, 16, 0, 0);
}

struct CellPar {
  const ushort* A0; const ushort* W0;   // bf16 segment 0 (A:[1024][512], W:[2048][512])
  const ushort* A1; const ushort* W1;   // bf16 segment 1 (null if absent)
  const float*  xs; const float* Ws; int ks;  // small-K fp32 part
  const float*  bias;                   // combined bias [2048]
  ushort* c; ushort* h_out;             // c stored bf16
};

// WG tile: 64 batch x 128 gate-rows (4g x 32h, h-major 64-row halves), 256 thr = 4 waves.
// K-chunk = 32 (nt = 16 per 512-K segment, up to 32 iters).
// Ring-4 x 12KB LDS (48KB -> 3 WG/CU), depth-3 prefetch, ONE barrier/iter,
// counted vmcnt(6) steady state (3 loads/thread/stage).
// Swizzle for 64B rows: chunk ^= (row>>1)&3 (pre-swizzled source + same XOR on read).
__device__ __forceinline__ void cell_body(const CellPar P, char* ldsb, int m0, int h0q)
{
  const int tid  = threadIdx.x;
  const int w    = tid >> 6, lane = tid & 63;
  const int wm   = w >> 1, wn = w & 1;
  const int colL = lane & 15, kgrp = lane >> 4;
  const int lr   = lane >> 2, lc = lane & 3;     // staging: row-in-16, chunk

  const ushort* Aseg[2] = { P.A0, P.A1 };
  const ushort* Wseg[2] = { P.W0, P.W1 };
  const int nt = (P.A1 != nullptr) ? 32 : 16;

  auto stage = [&](int buf, int it){
    const int seg = it >> 4;
    const int k0  = (it & 15) << 5;
    const ushort* A  = Aseg[seg];
    const ushort* Wt = Wseg[seg];
    ushort* Als = (ushort*)(ldsb + buf*12288);
    ushort* Bls = Als + 2048;                     // A: 64 rows x 32 = 4KB
    {                                             // A: 1 instr/thread (wave rows w*16..+15)
      const int r  = (w << 4) + lr;
      const int sw = (lc ^ ((r >> 1) & 3)) << 3;  // pre-swizzled source chunk
      gload16(A + (size_t)(m0 + r)*512 + k0 + sw, Als + (w << 9));
    }
    #pragma unroll
    for (int q = 0; q < 2; ++q){                  // B: 128 rows, 2 instr/thread
      const int r  = (q << 6) + (w << 4) + lr;
      const int g = (r >> 4) & 3, hp = r >> 6, hh = r & 15;
      const int sw = (lc ^ ((r >> 1) & 3)) << 3;
      gload16(Wt + ((size_t)(g << 9) + h0q + (hp << 4) + hh)*512 + k0 + sw,
              Bls + (q << 11) + (w << 9));
    }
  };

  f32x4 acc[2][4] = {};

  stage(0, 0);
  stage(1, 1);
  stage(2, 2);
  for (int it = 0; it < nt; ++it){
    if (it < nt - 2)       asm volatile("s_waitcnt vmcnt(6)" ::: "memory");
    else if (it == nt - 2) asm volatile("s_waitcnt vmcnt(3)" ::: "memory");
    else                   asm volatile("s_waitcnt vmcnt(0)" ::: "memory");
    __builtin_amdgcn_s_barrier();                 // stage(it) landed; iter it-1 reads done
    __builtin_amdgcn_sched_barrier(0);
    if (it + 3 < nt) stage((it + 3) & 3, it + 3);
    const ushort* Als = (const ushort*)(ldsb + (it & 3)*12288);
    const ushort* Bls = Als + 2048;
    const int ar0 = (wm << 5) + colL;
    const int ar1 = ar0 + 16;
    __builtin_amdgcn_s_setprio(1);
    bf16x8 av0 = *(const bf16x8*)(Als + ar0*32 + ((kgrp ^ ((ar0 >> 1) & 3)) << 3));
    bf16x8 av1 = *(const bf16x8*)(Als + ar1*32 + ((kgrp ^ ((ar1 >> 1) & 3)) << 3));
    #pragma unroll
    for (int nf = 0; nf < 4; ++nf){
      const int br = (wn << 6) + (nf << 4) + colL;
      bf16x8 bv = *(const bf16x8*)(Bls + br*32 + ((kgrp ^ ((br >> 1) & 3)) << 3));
      acc[0][nf] = __builtin_amdgcn_mfma_f32_16x16x32_bf16(av0, bv, acc[0][nf], 0, 0, 0);
      acc[1][nf] = __builtin_amdgcn_mfma_f32_16x16x32_bf16(av1, bv, acc[1][nf], 0, 0, 0);
    }
    __builtin_amdgcn_s_setprio(0);
    __builtin_amdgcn_sched_barrier(0);
  }

  // ---- epilogue (gate index = nf, purely in-register); c bf16 ----
  const int h = h0q + (wn << 4) + colL;
  float bia[4], wsv[4][4];
  #pragma unroll
  for (int g = 0; g < 4; ++g) bia[g] = P.bias[(g << 9) + h];
  if (P.ks > 0){
    #pragma unroll
    for (int g = 0; g < 4; ++g)
      #pragma unroll
      for (int k = 0; k < 4; ++k)
        wsv[g][k] = (k < P.ks) ? P.Ws[(size_t)((g << 9) + h)*P.ks + k] : 0.f;
  }
  #pragma unroll
  for (int mf = 0; mf < 2; ++mf){
    const int mB = m0 + (wm << 5) + (mf << 4) + (kgrp << 2);
    float xv[4][4];
    if (P.ks > 0){
      #pragma unroll
      for (int r = 0; r < 4; ++r)
        #pragma unroll
        for (int k = 0; k < 4; ++k)
          xv[r][k] = (k < P.ks) ? P.xs[(size_t)(mB + r)*P.ks + k] : 0.f;
    }
    #pragma unroll
    for (int r = 0; r < 4; ++r){
      const int m = mB + r;
      float gv[4];
      #pragma unroll
      for (int g = 0; g < 4; ++g){
        float t_ = acc[mf][g][r] + bia[g];
        if (P.ks > 0){
          #pragma unroll
          for (int k = 0; k < 4; ++k) t_ += xv[r][k]*wsv[g][k];
        }
        gv[g] = t_;
      }
      const float iG = fsig(gv[0]);
      const float fG = fsig(gv[1]);
      const float gG = ftanh(gv[2]);
      const float oG = fsig(gv[3]);
      const size_t off = (size_t)m*512 + h;
      const float cn = fG*bf2f(P.c[off]) + iG*gG;
      P.c[off] = f2bf(cn);
      P.h_out[off] = f2bf(oG*ftanh(cn));
    }
  }
}

// decoder/generic cell: grid 256, XCD-pinned h-tiles ({xcd, 8+xcd})
__global__ __launch_bounds__(256) void cell_k(CellPar P){
  __shared__ char lds[49152];
  const int f = blockIdx.x;
  const int xcd = f & 7, j = f >> 3;          // j 0..31
  const int bx = j & 15, u = j >> 4;          // u 0..1
  cell_body(P, lds, bx << 6, ((u << 3) + xcd) << 5);
}

struct EncP { const float* x; const float* Wih0f;
  const ushort *Whh0, *Wih1, *Whh1, *Wih2, *Whh2;
  const float* biases; ushort *h0, *h1, *h2; ushort *c0, *c1, *c2; };

// encoder wavefront step s (slot = writing-step & 1). grid 768:
// per XCD: 3 layers x h-tiles {xcd, 8+xcd} x 16 batch tiles.
__global__ __launch_bounds__(256) void enc_step_k(EncP E, int s){
  __shared__ char lds[49152];
  const int f = blockIdx.x;
  const int xcd = f & 7, j = f >> 3;          // j 0..95
  const int bx = j & 15, u = j >> 4;          // u 0..5
  const int l = u >> 1, ht = ((u & 1) << 3) + xcd;
  const int t = s - l;
  if (t < 0 || t > 63) return;
  const int p = s & 1;
  CellPar P;
  if (l == 0){
    P = { E.h0 + (size_t)(p^1)*HSZ, E.Whh0, nullptr, nullptr,
          E.x + (size_t)t*4096, E.Wih0f, 4,
          E.biases, E.c0, E.h0 + (size_t)p*HSZ };
  } else {
    const ushort* hlm1 = (l == 1) ? E.h0 : E.h1;
    ushort* hl         = (l == 1) ? E.h1 : E.h2;
    ushort* cl         = (l == 1) ? E.c1 : E.c2;
    const ushort* Wih  = (l == 1) ? E.Wih1 : E.Wih2;
    const ushort* Whh  = (l == 1) ? E.Whh1 : E.Whh2;
    P = { hlm1 + (size_t)(p^1)*HSZ, Wih,
          hl   + (size_t)(p^1)*HSZ, Whh,
          nullptr, nullptr, 0,
          E.biases + l*2048, cl, hl + (size_t)p*HSZ };
  }
  cell_body(P, lds, bx << 6, ht << 5);
}

// ---------------- small utility kernels ----------------
__global__ void f2b4(const float4* __restrict__ src, ushort4* __restrict__ dst, int n4){
  int i = blockIdx.x*blockDim.x + threadIdx.x;
  if (i < n4){
    float4 v = src[i];
    ushort4 r;
    r.x = f2bf(v.x); r.y = f2bf(v.y); r.z = f2bf(v.z); r.w = f2bf(v.w);
    dst[i] = r;
  }
}

__global__ void init_decin(const float* __restrict__ x, float* __restrict__ di){
  int i = blockIdx.x*blockDim.x + threadIdx.x;
  if (i < 2048){ int m = i >> 1, j = i & 1; di[i] = x[(size_t)63*4096 + m*4 + j]; }
}

__global__ void make_wcomb(const float* __restrict__ dWih0, const float* __restrict__ linW,
                           ushort* __restrict__ wc){
  int i = blockIdx.x*blockDim.x + threadIdx.x;
  if (i < 2048*512){
    int n = i >> 9, k = i & 511;
    wc[i] = f2bf(dWih0[n*2]*linW[k] + dWih0[n*2+1]*linW[512+k]);
  }
}

__global__ void prep_bias(const float* ebih0, const float* ebhh0,
                          const float* ebih, const float* ebhh,
                          const float* dbih0, const float* dbhh0,
                          const float* dbih, const float* dbhh,
                          const float* dWih0, const float* linb, float* bout){
  int n = blockIdx.x*blockDim.x + threadIdx.x;
  if (n >= 2048) return;
  bout[n]        = ebih0[n] + ebhh0[n];
  bout[2048+n]   = ebih[n] + ebhh[n];
  bout[2*2048+n] = ebih[2048+n] + ebhh[2048+n];
  float d0 = dbih0[n] + dbhh0[n];
  bout[3*2048+n] = d0;
  bout[4*2048+n] = d0 + dWih0[n*2]*linb[0] + dWih0[n*2+1]*linb[1];
  bout[5*2048+n] = dbih[n] + dbhh[n];
  bout[6*2048+n] = dbih[2048+n] + dbhh[2048+n];
}

__global__ __launch_bounds__(256) void out_linear(const ushort* __restrict__ h2,
    const float* __restrict__ linW, const float* __restrict__ linb, float* __restrict__ outp){
  int tid = threadIdx.x, w = tid >> 6, lane = tid & 63;
  int rbase = blockIdx.x*32 + w*8;
  for (int r = 0; r < 8; ++r){
    int m = rbase + r;
    float p0 = 0.f, p1 = 0.f;
    #pragma unroll
    for (int kk = 0; kk < 8; ++kk){
      int k = lane + kk*64;
      float hv = bf2f(h2[(size_t)m*512 + k]);
      p0 += hv * linW[k];
      p1 += hv * linW[512 + k];
    }
    #pragma unroll
    for (int off = 32; off > 0; off >>= 1){
      p0 += __shfl_down(p0, off);
      p1 += __shfl_down(p1, off);
    }
    if (lane == 0){
      outp[(size_t)m*2]   = p0 + linb[0];
      outp[(size_t)m*2+1] = p1 + linb[1];
    }
  }
}

__global__ __launch_bounds__(256) void dec_linear(const ushort* __restrict__ h2,
    const float* __restrict__ linW, const float* __restrict__ linb,
    float* __restrict__ outp, float* __restrict__ di){
  int tid = threadIdx.x, w = tid >> 6, lane = tid & 63;
  int mbase = blockIdx.x*32 + w*8;
  for (int r = 0; r < 8; ++r){
    int m = mbase + r;
    float p0 = 0.f, p1 = 0.f;
    #pragma unroll
    for (int kk = 0; kk < 8; ++kk){
      int k = lane + kk*64;
      float hv = bf2f(h2[(size_t)m*512 + k]);
      p0 += hv * linW[k];
      p1 += hv * linW[512 + k];
    }
    #pragma unroll
    for (int off = 32; off > 0; off >>= 1){
      p0 += __shfl_down(p0, off);
      p1 += __shfl_down(p1, off);
    }
    if (lane == 0){
      float o0 = p0 + linb[0], o1 = p1 + linb[1];
      outp[m*2]   = o0; outp[m*2+1] = o1;
      di[m*2]     = o0; di[m*2+1]   = o1;
    }
  }
}

extern "C" void kernel_launch(void* const* d_in, const int* in_sizes, int n_in,
                              void* d_out, int out_size, void* d_ws, size_t ws_size,
                              hipStream_t stream)
{
  const float* x        = (const float*)d_in[0];
  const float* enc_Wih0 = (const float*)d_in[1];
  const float* enc_Whh0 = (const float*)d_in[2];
  const float* enc_bih0 = (const float*)d_in[3];
  const float* enc_bhh0 = (const float*)d_in[4];
  const float* enc_Wih  = (const float*)d_in[5];
  const float* enc_Whh  = (const float*)d_in[6];
  const float* enc_bih  = (const float*)d_in[7];
  const float* enc_bhh  = (const float*)d_in[8];
  const float* dec_Wih0 = (const float*)d_in[9];
  const float* dec_Whh0 = (const float*)d_in[10];
  const float* dec_bih0 = (const float*)d_in[11];
  const float* dec_bhh0 = (const float*)d_in[12];
  const float* dec_Wih  = (const float*)d_in[13];
  const float* dec_Whh  = (const float*)d_in[14];
  const float* dec_bih  = (const float*)d_in[15];
  const float* dec_bhh  = (const float*)d_in[16];
  const float* lin_W    = (const float*)d_in[17];
  const float* lin_b    = (const float*)d_in[18];

  const bool big = ws_size >= 69271552ull;

  ushort* wb     = (ushort*)d_ws;
  ushort* eWhh0b = wb;
  ushort* eWihb  = wb + (size_t)WSZ;
  ushort* eWhhb  = wb + 3*(size_t)WSZ;
  ushort* dWhh0b = wb + 5*(size_t)WSZ;
  ushort* dWihb  = wb + 6*(size_t)WSZ;
  ushort* dWhhb  = wb + 8*(size_t)WSZ;
  ushort* wcombb = wb + 10*(size_t)WSZ;                   // big only
  ushort* hbuf   = wb + (big ? 11 : 10)*(size_t)WSZ;      // 6 HSZ (3 layers x 2 slots)
  ushort* h2hist = hbuf + 6*(size_t)HSZ;                  // big: 32 HSZ
  ushort* cbuf   = h2hist + (big ? 32*(size_t)HSZ : 0);   // bf16 c, 3 HSZ
  float*  dec_in = (float*)(cbuf + 3*(size_t)HSZ);
  float*  biases = dec_in + 2048;

  ushort* h0 = hbuf;
  ushort* h1 = hbuf + 2*(size_t)HSZ;
  ushort* h2 = hbuf + 4*(size_t)HSZ;
  ushort *c0 = cbuf, *c1 = cbuf + (size_t)HSZ, *c2 = cbuf + 2*(size_t)HSZ;

  hipMemsetAsync(hbuf, 0, 6*(size_t)HSZ*2, stream);
  hipMemsetAsync(cbuf, 0, 3*(size_t)HSZ*2, stream);

  const int thr = 256;
  {
    struct { const float* s; ushort* d; size_t n; } cv[6] = {
      {enc_Whh0, eWhh0b, WSZ}, {enc_Wih, eWihb, 2*(size_t)WSZ}, {enc_Whh, eWhhb, 2*(size_t)WSZ},
      {dec_Whh0, dWhh0b, WSZ}, {dec_Wih, dWihb, 2*(size_t)WSZ}, {dec_Whh, dWhhb, 2*(size_t)WSZ},
    };
    for (int i = 0; i < 6; ++i){
      int n4 = (int)(cv[i].n/4);
      f2b4<<<(n4+thr-1)/thr, thr, 0, stream>>>((const float4*)cv[i].s, (ushort4*)cv[i].d, n4);
    }
  }
  if (big) make_wcomb<<<4096, thr, 0, stream>>>(dec_Wih0, lin_W, wcombb);
  prep_bias<<<8, thr, 0, stream>>>(enc_bih0, enc_bhh0, enc_bih, enc_bhh,
                                   dec_bih0, dec_bhh0, dec_bih, dec_bhh,
                                   dec_Wih0, lin_b, biases);
  init_decin<<<8, thr, 0, stream>>>(x, dec_in);

  EncP EP = { x, enc_Wih0, eWhh0b, eWihb, eWhhb, eWihb + (size_t)WSZ, eWhhb + (size_t)WSZ,
              biases, h0, h1, h2, c0, c1, c2 };

  // ---- encoder: 66 wavefront-step launches, 768 WGs (3 WG/CU) ----
  for (int s = 0; s < 66; ++s)
    enc_step_k<<<768, thr, 0, stream>>>(EP, s);

  // encoder finals (step-parity slots): l0 @s=63 -> 1, l1 @s=64 -> 0, l2 @s=65 -> 1
  int cur0 = 1, cur1 = 0, cur2 = 1;

  // ---- decoder ----
  if (big){
    for (int t = 0; t < 32; ++t){
      CellPar P0;
      if (t == 0)
        P0 = { h0 + (size_t)cur0*HSZ, dWhh0b, nullptr, nullptr,
               dec_in, dec_Wih0, 2, biases + 3*2048, c0, h0 + (size_t)(cur0^1)*HSZ };
      else
        P0 = { h2hist + (size_t)(t-1)*HSZ, wcombb, h0 + (size_t)cur0*HSZ, dWhh0b,
               nullptr, nullptr, 0, biases + 4*2048, c0, h0 + (size_t)(cur0^1)*HSZ };
      cell_k<<<256, thr, 0, stream>>>(P0); cur0 ^= 1;

      CellPar P1 = { h0 + (size_t)cur0*HSZ, dWihb, h1 + (size_t)cur1*HSZ, dWhhb,
                     nullptr, nullptr, 0, biases + 5*2048, c1, h1 + (size_t)(cur1^1)*HSZ };
      cell_k<<<256, thr, 0, stream>>>(P1); cur1 ^= 1;

      const ushort* a2prev = (t == 0) ? (h2 + (size_t)cur2*HSZ) : (h2hist + (size_t)(t-1)*HSZ);
      CellPar P2 = { h1 + (size_t)cur1*HSZ, dWihb + (size_t)WSZ, a2prev, dWhhb + (size_t)WSZ,
                     nullptr, nullptr, 0, biases + 6*2048, c2, h2hist + (size_t)t*HSZ };
      cell_k<<<256, thr, 0, stream>>>(P2);
    }
    out_linear<<<1024, thr, 0, stream>>>(h2hist, lin_W, lin_b, (float*)d_out);
  } else {
    for (int t = 0; t < 32; ++t){
      CellPar P0 = { h0 + (size_t)cur0*HSZ, dWhh0b, nullptr, nullptr,
                     dec_in, dec_Wih0, 2, biases + 3*2048, c0, h0 + (size_t)(cur0^1)*HSZ };
      cell_k<<<256, thr, 0, stream>>>(P0); cur0 ^= 1;

      CellPar P1 = { h0 + (size_t)cur0*HSZ, dWihb, h1 + (size_t)cur1*HSZ, dWhhb,
                     nullptr, nullptr, 0, biases + 5*2048, c1, h1 + (size_t)(cur1^1)*HSZ };
      cell_k<<<256, thr, 0, stream>>>(P1); cur1 ^= 1;

      CellPar P2 = { h1 + (size_t)cur1*HSZ, dWihb + (size_t)WSZ,
                     h2 + (size_t)cur2*HSZ, dWhhb + (size_t)WSZ,
                     nullptr, nullptr, 0, biases + 6*2048, c2, h2 + (size_t)(cur2^1)*HSZ };
      cell_k<<<256, thr, 0, stream>>>(P2); cur2 ^= 1;

      dec_linear<<<32, thr, 0, stream>>>(h2 + (size_t)cur2*HSZ, lin_W, lin_b,
                                         (float*)d_out + (size_t)t*2048, dec_in);
    }
  }
}

// Round 12
// 2820.091 us; speedup vs baseline: 1.7943x; 1.0939x over previous
//
#include <hip/hip_runtime.h>
#include <hip/hip_bf16.h>

typedef __bf16 bf16x8 __attribute__((ext_vector_type(8)));
typedef float f32x4 __attribute__((ext_vector_type(4)));

#define HSZ (1024*512)      // h/c slot elems
#define WSZ (2048*512)      // weight matrix elems

__device__ __forceinline__ float fsig(float x){ return 1.0f/(1.0f+__expf(-x)); }
__device__ __forceinline__ float ftanh(float x){ return 1.0f - 2.0f/(__expf(2.0f*x)+1.0f); }
__device__ __forceinline__ float bf2f(ushort u){ return __uint_as_float(((unsigned)u) << 16); }
__device__ __forceinline__ ushort f2bf(float f){
  __hip_bfloat16 b = __float2bfloat16(f);
  return *reinterpret_cast<const ushort*>(&b);
}

__device__ __forceinline__ void gload16(const void* g, void* l){
  __builtin_amdgcn_global_load_lds((const __attribute__((address_space(1))) void*)g,
                                   (__attribute__((address_space(3))) void*)l, 16, 0, 0);
}

struct CellPar {
  const ushort* A0; const ushort* W0;   // bf16 segment 0 (A:[1024][512], W:[2048][512])
  const ushort* A1; const ushort* W1;   // bf16 segment 1 (null if absent)
  const float*  xs; const float* Ws; int ks;  // small-K fp32 part
  const float*  bias;                   // combined bias [2048]
  ushort* c; ushort* h_out;             // c stored bf16
};

// WG tile: 64 batch x 128 gate-rows (4g x 32h, h-major 64-row halves), 256 thr = 4 waves.
// K-chunk = 32; ring-4 x 12KB = 48KB (3 WG/CU). Main loop consumes TWO chunk-buffers
// per barrier period (64-K per period -> 16 MFMA/wave/period, HALF of R4's barriers),
// prefetch cover ~1 full period. Swizzle (R11-proven): chunk ^= (row>>1)&3.
__device__ __forceinline__ void cell_body(const CellPar P, char* ldsb, int m0, int h0q)
{
  const int tid  = threadIdx.x;
  const int w    = tid >> 6, lane = tid & 63;
  const int wm   = w >> 1, wn = w & 1;
  const int colL = lane & 15, kgrp = lane >> 4;
  const int lr   = lane >> 2, lc = lane & 3;     // staging: row-in-16, chunk

  const ushort* Aseg[2] = { P.A0, P.A1 };
  const ushort* Wseg[2] = { P.W0, P.W1 };
  const int NC = (P.A1 != nullptr) ? 32 : 16;    // 32-K chunks total

  auto stage = [&](int buf, int j){
    const int seg = j >> 4;
    const int k0  = (j & 15) << 5;
    const ushort* A  = Aseg[seg];
    const ushort* Wt = Wseg[seg];
    ushort* Als = (ushort*)(ldsb + buf*12288);
    ushort* Bls = Als + 2048;                     // A: 64 rows x 32 = 4KB
    {                                             // A: 1 instr/thread (wave rows w*16..+15)
      const int r  = (w << 4) + lr;
      const int sw = (lc ^ ((r >> 1) & 3)) << 3;  // pre-swizzled source chunk
      gload16(A + (size_t)(m0 + r)*512 + k0 + sw, Als + (w << 9));
    }
    #pragma unroll
    for (int q = 0; q < 2; ++q){                  // B: 128 rows, 2 instr/thread
      const int r  = (q << 6) + (w << 4) + lr;
      const int g = (r >> 4) & 3, hp = r >> 6, hh = r & 15;
      const int sw = (lc ^ ((r >> 1) & 3)) << 3;
      gload16(Wt + ((size_t)(g << 9) + h0q + (hp << 4) + hh)*512 + k0 + sw,
              Bls + (q << 11) + (w << 9));
    }
  };

  f32x4 acc[2][4] = {};

  stage(0, 0); stage(1, 1); stage(2, 2); stage(3, 3);
  const int np = NC >> 1;                         // barrier periods (64-K each)
  const int ar0 = (wm << 5) + colL;
  const int ar1 = ar0 + 16;
  for (int i = 0; i < np; ++i){
    if (i + 1 < np) asm volatile("s_waitcnt vmcnt(6)" ::: "memory");   // chunks 2i,2i+1 landed
    else            asm volatile("s_waitcnt vmcnt(0)" ::: "memory");
    __builtin_amdgcn_s_barrier();
    __builtin_amdgcn_sched_barrier(0);
    __builtin_amdgcn_s_setprio(1);
    #pragma unroll
    for (int sub = 0; sub < 2; ++sub){
      const int b = ((i << 1) + sub) & 3;
      const ushort* Als = (const ushort*)(ldsb + b*12288);
      const ushort* Bls = Als + 2048;
      bf16x8 av0 = *(const bf16x8*)(Als + ar0*32 + ((kgrp ^ ((ar0 >> 1) & 3)) << 3));
      bf16x8 av1 = *(const bf16x8*)(Als + ar1*32 + ((kgrp ^ ((ar1 >> 1) & 3)) << 3));
      #pragma unroll
      for (int nf = 0; nf < 4; ++nf){
        const int br = (wn << 6) + (nf << 4) + colL;
        bf16x8 bv = *(const bf16x8*)(Bls + br*32 + ((kgrp ^ ((br >> 1) & 3)) << 3));
        acc[0][nf] = __builtin_amdgcn_mfma_f32_16x16x32_bf16(av0, bv, acc[0][nf], 0, 0, 0);
        acc[1][nf] = __builtin_amdgcn_mfma_f32_16x16x32_bf16(av1, bv, acc[1][nf], 0, 0, 0);
      }
    }
    __builtin_amdgcn_s_setprio(0);
    __builtin_amdgcn_sched_barrier(0);
    __builtin_amdgcn_s_barrier();                 // reads of buffers 2i,2i+1 done
    const int j0 = (i << 1) + 4;
    if (j0 < NC){                                 // refill the two freed buffers
      stage(j0 & 3, j0);
      stage((j0 + 1) & 3, j0 + 1);
    }
  }

  // ---- epilogue (gate index = nf, purely in-register); c bf16 ----
  const int h = h0q + (wn << 4) + colL;
  float bia[4], wsv[4][4];
  #pragma unroll
  for (int g = 0; g < 4; ++g) bia[g] = P.bias[(g << 9) + h];
  if (P.ks > 0){
    #pragma unroll
    for (int g = 0; g < 4; ++g)
      #pragma unroll
      for (int k = 0; k < 4; ++k)
        wsv[g][k] = (k < P.ks) ? P.Ws[(size_t)((g << 9) + h)*P.ks + k] : 0.f;
  }
  #pragma unroll
  for (int mf = 0; mf < 2; ++mf){
    const int mB = m0 + (wm << 5) + (mf << 4) + (kgrp << 2);
    float xv[4][4];
    if (P.ks > 0){
      #pragma unroll
      for (int r = 0; r < 4; ++r)
        #pragma unroll
        for (int k = 0; k < 4; ++k)
          xv[r][k] = (k < P.ks) ? P.xs[(size_t)(mB + r)*P.ks + k] : 0.f;
    }
    #pragma unroll
    for (int r = 0; r < 4; ++r){
      const int m = mB + r;
      float gv[4];
      #pragma unroll
      for (int g = 0; g < 4; ++g){
        float t_ = acc[mf][g][r] + bia[g];
        if (P.ks > 0){
          #pragma unroll
          for (int k = 0; k < 4; ++k) t_ += xv[r][k]*wsv[g][k];
        }
        gv[g] = t_;
      }
      const float iG = fsig(gv[0]);
      const float fG = fsig(gv[1]);
      const float gG = ftanh(gv[2]);
      const float oG = fsig(gv[3]);
      const size_t off = (size_t)m*512 + h;
      const float cn = fG*bf2f(P.c[off]) + iG*gG;
      P.c[off] = f2bf(cn);
      P.h_out[off] = f2bf(oG*ftanh(cn));
    }
  }
}

// decoder/generic cell: grid 256, XCD-pinned h-tiles ({xcd, 8+xcd})
__global__ __launch_bounds__(256) void cell_k(CellPar P){
  __shared__ char lds[49152];
  const int f = blockIdx.x;
  const int xcd = f & 7, j = f >> 3;          // j 0..31
  const int bx = j & 15, u = j >> 4;          // u 0..1
  cell_body(P, lds, bx << 6, ((u << 3) + xcd) << 5);
}

struct EncP { const float* x; const float* Wih0f;
  const ushort *Whh0, *Wih1, *Whh1, *Wih2, *Whh2;
  const float* biases; ushort *h0, *h1, *h2; ushort *c0, *c1, *c2; };

// encoder wavefront step s (slot = writing-step & 1). grid 768:
// per XCD: 3 layers x h-tiles {xcd, 8+xcd} x 16 batch tiles.
__global__ __launch_bounds__(256) void enc_step_k(EncP E, int s){
  __shared__ char lds[49152];
  const int f = blockIdx.x;
  const int xcd = f & 7, j = f >> 3;          // j 0..95
  const int bx = j & 15, u = j >> 4;          // u 0..5
  const int l = u >> 1, ht = ((u & 1) << 3) + xcd;
  const int t = s - l;
  if (t < 0 || t > 63) return;
  const int p = s & 1;
  CellPar P;
  if (l == 0){
    P = { E.h0 + (size_t)(p^1)*HSZ, E.Whh0, nullptr, nullptr,
          E.x + (size_t)t*4096, E.Wih0f, 4,
          E.biases, E.c0, E.h0 + (size_t)p*HSZ };
  } else {
    const ushort* hlm1 = (l == 1) ? E.h0 : E.h1;
    ushort* hl         = (l == 1) ? E.h1 : E.h2;
    ushort* cl         = (l == 1) ? E.c1 : E.c2;
    const ushort* Wih  = (l == 1) ? E.Wih1 : E.Wih2;
    const ushort* Whh  = (l == 1) ? E.Whh1 : E.Whh2;
    P = { hlm1 + (size_t)(p^1)*HSZ, Wih,
          hl   + (size_t)(p^1)*HSZ, Whh,
          nullptr, nullptr, 0,
          E.biases + l*2048, cl, hl + (size_t)p*HSZ };
  }
  cell_body(P, lds, bx << 6, ht << 5);
}

// ---------------- small utility kernels ----------------
__global__ void f2b4(const float4* __restrict__ src, ushort4* __restrict__ dst, int n4){
  int i = blockIdx.x*blockDim.x + threadIdx.x;
  if (i < n4){
    float4 v = src[i];
    ushort4 r;
    r.x = f2bf(v.x); r.y = f2bf(v.y); r.z = f2bf(v.z); r.w = f2bf(v.w);
    dst[i] = r;
  }
}

__global__ void init_decin(const float* __restrict__ x, float* __restrict__ di){
  int i = blockIdx.x*blockDim.x + threadIdx.x;
  if (i < 2048){ int m = i >> 1, j = i & 1; di[i] = x[(size_t)63*4096 + m*4 + j]; }
}

__global__ void make_wcomb(const float* __restrict__ dWih0, const float* __restrict__ linW,
                           ushort* __restrict__ wc){
  int i = blockIdx.x*blockDim.x + threadIdx.x;
  if (i < 2048*512){
    int n = i >> 9, k = i & 511;
    wc[i] = f2bf(dWih0[n*2]*linW[k] + dWih0[n*2+1]*linW[512+k]);
  }
}

__global__ void prep_bias(const float* ebih0, const float* ebhh0,
                          const float* ebih, const float* ebhh,
                          const float* dbih0, const float* dbhh0,
                          const float* dbih, const float* dbhh,
                          const float* dWih0, const float* linb, float* bout){
  int n = blockIdx.x*blockDim.x + threadIdx.x;
  if (n >= 2048) return;
  bout[n]        = ebih0[n] + ebhh0[n];
  bout[2048+n]   = ebih[n] + ebhh[n];
  bout[2*2048+n] = ebih[2048+n] + ebhh[2048+n];
  float d0 = dbih0[n] + dbhh0[n];
  bout[3*2048+n] = d0;
  bout[4*2048+n] = d0 + dWih0[n*2]*linb[0] + dWih0[n*2+1]*linb[1];
  bout[5*2048+n] = dbih[n] + dbhh[n];
  bout[6*2048+n] = dbih[2048+n] + dbhh[2048+n];
}

__global__ __launch_bounds__(256) void out_linear(const ushort* __restrict__ h2,
    const float* __restrict__ linW, const float* __restrict__ linb, float* __restrict__ outp){
  int tid = threadIdx.x, w = tid >> 6, lane = tid & 63;
  int rbase = blockIdx.x*32 + w*8;
  for (int r = 0; r < 8; ++r){
    int m = rbase + r;
    float p0 = 0.f, p1 = 0.f;
    #pragma unroll
    for (int kk = 0; kk < 8; ++kk){
      int k = lane + kk*64;
      float hv = bf2f(h2[(size_t)m*512 + k]);
      p0 += hv * linW[k];
      p1 += hv * linW[512 + k];
    }
    #pragma unroll
    for (int off = 32; off > 0; off >>= 1){
      p0 += __shfl_down(p0, off);
      p1 += __shfl_down(p1, off);
    }
    if (lane == 0){
      outp[(size_t)m*2]   = p0 + linb[0];
      outp[(size_t)m*2+1] = p1 + linb[1];
    }
  }
}

__global__ __launch_bounds__(256) void dec_linear(const ushort* __restrict__ h2,
    const float* __restrict__ linW, const float* __restrict__ linb,
    float* __restrict__ outp, float* __restrict__ di){
  int tid = threadIdx.x, w = tid >> 6, lane = tid & 63;
  int mbase = blockIdx.x*32 + w*8;
  for (int r = 0; r < 8; ++r){
    int m = mbase + r;
    float p0 = 0.f, p1 = 0.f;
    #pragma unroll
    for (int kk = 0; kk < 8; ++kk){
      int k = lane + kk*64;
      float hv = bf2f(h2[(size_t)m*512 + k]);
      p0 += hv * linW[k];
      p1 += hv * linW[512 + k];
    }
    #pragma unroll
    for (int off = 32; off > 0; off >>= 1){
      p0 += __shfl_down(p0, off);
      p1 += __shfl_down(p1, off);
    }
    if (lane == 0){
      float o0 = p0 + linb[0], o1 = p1 + linb[1];
      outp[m*2]   = o0; outp[m*2+1] = o1;
      di[m*2]     = o0; di[m*2+1]   = o1;
    }
  }
}

extern "C" void kernel_launch(void* const* d_in, const int* in_sizes, int n_in,
                              void* d_out, int out_size, void* d_ws, size_t ws_size,
                              hipStream_t stream)
{
  const float* x        = (const float*)d_in[0];
  const float* enc_Wih0 = (const float*)d_in[1];
  const float* enc_Whh0 = (const float*)d_in[2];
  const float* enc_bih0 = (const float*)d_in[3];
  const float* enc_bhh0 = (const float*)d_in[4];
  const float* enc_Wih  = (const float*)d_in[5];
  const float* enc_Whh  = (const float*)d_in[6];
  const float* enc_bih  = (const float*)d_in[7];
  const float* enc_bhh  = (const float*)d_in[8];
  const float* dec_Wih0 = (const float*)d_in[9];
  const float* dec_Whh0 = (const float*)d_in[10];
  const float* dec_bih0 = (const float*)d_in[11];
  const float* dec_bhh0 = (const float*)d_in[12];
  const float* dec_Wih  = (const float*)d_in[13];
  const float* dec_Whh  = (const float*)d_in[14];
  const float* dec_bih  = (const float*)d_in[15];
  const float* dec_bhh  = (const float*)d_in[16];
  const float* lin_W    = (const float*)d_in[17];
  const float* lin_b    = (const float*)d_in[18];

  const bool big = ws_size >= 69271552ull;

  ushort* wb     = (ushort*)d_ws;
  ushort* eWhh0b = wb;
  ushort* eWihb  = wb + (size_t)WSZ;
  ushort* eWhhb  = wb + 3*(size_t)WSZ;
  ushort* dWhh0b = wb + 5*(size_t)WSZ;
  ushort* dWihb  = wb + 6*(size_t)WSZ;
  ushort* dWhhb  = wb + 8*(size_t)WSZ;
  ushort* wcombb = wb + 10*(size_t)WSZ;                   // big only
  ushort* hbuf   = wb + (big ? 11 : 10)*(size_t)WSZ;      // 6 HSZ (3 layers x 2 slots)
  ushort* h2hist = hbuf + 6*(size_t)HSZ;                  // big: 32 HSZ
  ushort* cbuf   = h2hist + (big ? 32*(size_t)HSZ : 0);   // bf16 c, 3 HSZ
  float*  dec_in = (float*)(cbuf + 3*(size_t)HSZ);
  float*  biases = dec_in + 2048;

  ushort* h0 = hbuf;
  ushort* h1 = hbuf + 2*(size_t)HSZ;
  ushort* h2 = hbuf + 4*(size_t)HSZ;
  ushort *c0 = cbuf, *c1 = cbuf + (size_t)HSZ, *c2 = cbuf + 2*(size_t)HSZ;

  hipMemsetAsync(hbuf, 0, 6*(size_t)HSZ*2, stream);
  hipMemsetAsync(cbuf, 0, 3*(size_t)HSZ*2, stream);

  const int thr = 256;
  {
    struct { const float* s; ushort* d; size_t n; } cv[6] = {
      {enc_Whh0, eWhh0b, WSZ}, {enc_Wih, eWihb, 2*(size_t)WSZ}, {enc_Whh, eWhhb, 2*(size_t)WSZ},
      {dec_Whh0, dWhh0b, WSZ}, {dec_Wih, dWihb, 2*(size_t)WSZ}, {dec_Whh, dWhhb, 2*(size_t)WSZ},
    };
    for (int i = 0; i < 6; ++i){
      int n4 = (int)(cv[i].n/4);
      f2b4<<<(n4+thr-1)/thr, thr, 0, stream>>>((const float4*)cv[i].s, (ushort4*)cv[i].d, n4);
    }
  }
  if (big) make_wcomb<<<4096, thr, 0, stream>>>(dec_Wih0, lin_W, wcombb);
  prep_bias<<<8, thr, 0, stream>>>(enc_bih0, enc_bhh0, enc_bih, enc_bhh,
                                   dec_bih0, dec_bhh0, dec_bih, dec_bhh,
                                   dec_Wih0, lin_b, biases);
  init_decin<<<8, thr, 0, stream>>>(x, dec_in);

  EncP EP = { x, enc_Wih0, eWhh0b, eWihb, eWhhb, eWihb + (size_t)WSZ, eWhhb + (size_t)WSZ,
              biases, h0, h1, h2, c0, c1, c2 };

  // ---- encoder: 66 wavefront-step launches, 768 WGs (3 WG/CU) ----
  for (int s = 0; s < 66; ++s)
    enc_step_k<<<768, thr, 0, stream>>>(EP, s);

  // encoder finals (step-parity slots): l0 @s=63 -> 1, l1 @s=64 -> 0, l2 @s=65 -> 1
  int cur0 = 1, cur1 = 0, cur2 = 1;

  // ---- decoder ----
  if (big){
    for (int t = 0; t < 32; ++t){
      CellPar P0;
      if (t == 0)
        P0 = { h0 + (size_t)cur0*HSZ, dWhh0b, nullptr, nullptr,
               dec_in, dec_Wih0, 2, biases + 3*2048, c0, h0 + (size_t)(cur0^1)*HSZ };
      else
        P0 = { h2hist + (size_t)(t-1)*HSZ, wcombb, h0 + (size_t)cur0*HSZ, dWhh0b,
               nullptr, nullptr, 0, biases + 4*2048, c0, h0 + (size_t)(cur0^1)*HSZ };
      cell_k<<<256, thr, 0, stream>>>(P0); cur0 ^= 1;

      CellPar P1 = { h0 + (size_t)cur0*HSZ, dWihb, h1 + (size_t)cur1*HSZ, dWhhb,
                     nullptr, nullptr, 0, biases + 5*2048, c1, h1 + (size_t)(cur1^1)*HSZ };
      cell_k<<<256, thr, 0, stream>>>(P1); cur1 ^= 1;

      const ushort* a2prev = (t == 0) ? (h2 + (size_t)cur2*HSZ) : (h2hist + (size_t)(t-1)*HSZ);
      CellPar P2 = { h1 + (size_t)cur1*HSZ, dWihb + (size_t)WSZ, a2prev, dWhhb + (size_t)WSZ,
                     nullptr, nullptr, 0, biases + 6*2048, c2, h2hist + (size_t)t*HSZ };
      cell_k<<<256, thr, 0, stream>>>(P2);
    }
    out_linear<<<1024, thr, 0, stream>>>(h2hist, lin_W, lin_b, (float*)d_out);
  } else {
    for (int t = 0; t < 32; ++t){
      CellPar P0 = { h0 + (size_t)cur0*HSZ, dWhh0b, nullptr, nullptr,
                     dec_in, dec_Wih0, 2, biases + 3*2048, c0, h0 + (size_t)(cur0^1)*HSZ };
      cell_k<<<256, thr, 0, stream>>>(P0); cur0 ^= 1;

      CellPar P1 = { h0 + (size_t)cur0*HSZ, dWihb, h1 + (size_t)cur1*HSZ, dWhhb,
                     nullptr, nullptr, 0, biases + 5*2048, c1, h1 + (size_t)(cur1^1)*HSZ };
      cell_k<<<256, thr, 0, stream>>>(P1); cur1 ^= 1;

      CellPar P2 = { h1 + (size_t)cur1*HSZ, dWihb + (size_t)WSZ,
                     h2 + (size_t)cur2*HSZ, dWhhb + (size_t)WSZ,
                     nullptr, nullptr, 0, biases + 6*2048, c2, h2 + (size_t)(cur2^1)*HSZ };
      cell_k<<<256, thr, 0, stream>>>(P2); cur2 ^= 1;

      dec_linear<<<32, thr, 0, stream>>>(h2 + (size_t)cur2*HSZ, lin_W, lin_b,
                                         (float*)d_out + (size_t)t*2048, dec_in);
    }
  }
}